// Round 7
// baseline (226.582 us; speedup 1.0000x reference)
//
#include <hip/hip_runtime.h>
#include <hip/hip_bf16.h>

typedef __bf16 bf16;
typedef __bf16 bf16x8 __attribute__((ext_vector_type(8)));
typedef __bf16 bf16x4 __attribute__((ext_vector_type(4)));
typedef float  f32x4  __attribute__((ext_vector_type(4)));
typedef float  f32x16 __attribute__((ext_vector_type(16)));

#define AS1 __attribute__((address_space(1)))
#define AS3 __attribute__((address_space(3)))

__device__ __forceinline__ void gload_lds16(const bf16* g, bf16* l) {
    __builtin_amdgcn_global_load_lds((const AS1 unsigned int*)g,
                                     (AS3 unsigned int*)l, 16, 0, 0);
}

// ------- cast fp32 -> bf16 (7 tensors) + mask bias, via grid.z -------
__global__ __launch_bounds__(256) void cast8_k(
    const float* __restrict__ s0, const float* __restrict__ s1,
    const float* __restrict__ s2, const float* __restrict__ s3,
    const float* __restrict__ s4, const float* __restrict__ s5,
    const float* __restrict__ s6,
    bf16* __restrict__ d0, bf16* __restrict__ d1, bf16* __restrict__ d2,
    bf16* __restrict__ d3, bf16* __restrict__ d4, bf16* __restrict__ d5,
    bf16* __restrict__ d6,
    const int* __restrict__ m, float* __restrict__ mb,
    int n_big, int n_small) {
    int z = blockIdx.z;
    int i = (blockIdx.x * 256 + threadIdx.x) * 8;
    if (z == 7) {  // mask -> exp2-domain additive bias
        if (i >= 4096) return;
        int4 a = *(const int4*)(m + i);
        int4 b = *(const int4*)(m + i + 4);
        float4 o0, o1;
        o0.x = (a.x == 0) ? -1.442695e9f : -17.3123405f;
        o0.y = (a.y == 0) ? -1.442695e9f : -17.3123405f;
        o0.z = (a.z == 0) ? -1.442695e9f : -17.3123405f;
        o0.w = (a.w == 0) ? -1.442695e9f : -17.3123405f;
        o1.x = (b.x == 0) ? -1.442695e9f : -17.3123405f;
        o1.y = (b.y == 0) ? -1.442695e9f : -17.3123405f;
        o1.z = (b.z == 0) ? -1.442695e9f : -17.3123405f;
        o1.w = (b.w == 0) ? -1.442695e9f : -17.3123405f;
        *(float4*)(mb + i) = o0;
        *(float4*)(mb + i + 4) = o1;
        return;
    }
    const float* s = (z == 0) ? s0 : (z == 1) ? s1 : (z == 2) ? s2
                   : (z == 3) ? s3 : (z == 4) ? s4 : (z == 5) ? s5 : s6;
    bf16* d = (z == 0) ? d0 : (z == 1) ? d1 : (z == 2) ? d2
            : (z == 3) ? d3 : (z == 4) ? d4 : (z == 5) ? d5 : d6;
    int n = (z < 3) ? n_big : n_small;
    if (i >= n) return;
    float4 a = *(const float4*)(s + i);
    float4 b = *(const float4*)(s + i + 4);
    bf16x8 o;
    o[0] = (bf16)a.x; o[1] = (bf16)a.y; o[2] = (bf16)a.z; o[3] = (bf16)a.w;
    o[4] = (bf16)b.x; o[5] = (bf16)b.y; o[6] = (bf16)b.z; o[7] = (bf16)b.w;
    *(bf16x8*)(d + i) = o;
}

// ---------------- BT-GEMM, 32x32x16 MFMA, 128x128 tile ----------------
// LDS passed in (hoisted to kernel scope) so multiple instantiations in one
// kernel share the same 32 KB instead of stacking to 64 KB.
// TRANS=true: compute C^T and store to VpT with the bit2<->bit3 key
// permutation baked in (for attn's PV A-frag trick).
template <typename OUT_T, bool TRANS>
__device__ __forceinline__ void gemm32_core(
    bf16* Asm, bf16* Bsm,
    const bf16* __restrict__ A, const bf16* __restrict__ W,
    const float* __restrict__ bias, OUT_T* __restrict__ C,
    int m0, int n0, int N, int K) {
    const int lane = threadIdx.x & 63;
    const int w = threadIdx.x >> 6;
    const int l31 = lane & 31;
    const int h = lane >> 5;
    const int x7 = l31 & 7;
    const int srow = lane >> 3;
    const int scol = ((lane & 7) ^ srow) * 8;
    const int wm = (w & 1) * 64;
    const int wn = (w >> 1) * 64;

    f32x16 acc[2][2] = {};

    for (int k0 = 0; k0 < K; k0 += 64) {
#pragma unroll
        for (int c = 0; c < 4; ++c) {
            int r = w * 32 + c * 8;
            gload_lds16(A + (size_t)(m0 + r + srow) * K + k0 + scol, &Asm[r * 64]);
            gload_lds16(W + (size_t)(n0 + r + srow) * K + k0 + scol, &Bsm[r * 64]);
        }
        __syncthreads();
#pragma unroll
        for (int step = 0; step < 4; ++step) {
            bf16x8 af[2], bfv[2];
#pragma unroll
            for (int i = 0; i < 2; ++i)
                af[i] = *(const bf16x8*)&Asm[(wm + i * 32 + l31) * 64 +
                                             (((step * 2 + h) ^ x7) * 8)];
#pragma unroll
            for (int j = 0; j < 2; ++j)
                bfv[j] = *(const bf16x8*)&Bsm[(wn + j * 32 + l31) * 64 +
                                              (((step * 2 + h) ^ x7) * 8)];
#pragma unroll
            for (int i = 0; i < 2; ++i)
#pragma unroll
                for (int j = 0; j < 2; ++j)
                    acc[i][j] = TRANS
                        ? __builtin_amdgcn_mfma_f32_32x32x16_bf16(bfv[j], af[i],
                                                                  acc[i][j], 0, 0, 0)
                        : __builtin_amdgcn_mfma_f32_32x32x16_bf16(af[i], bfv[j],
                                                                  acc[i][j], 0, 0, 0);
        }
        __syncthreads();
    }
    if (!TRANS) {
#pragma unroll
        for (int i = 0; i < 2; ++i)
#pragma unroll
            for (int j = 0; j < 2; ++j) {
                int col = n0 + wn + j * 32 + l31;
                float bv = bias[col];
#pragma unroll
                for (int g = 0; g < 4; ++g)
#pragma unroll
                    for (int rr = 0; rr < 4; ++rr) {
                        int row = m0 + wm + i * 32 + rr + g * 8 + 4 * h;
                        C[(size_t)row * N + col] =
                            (OUT_T)(acc[i][j][g * 4 + rr] + bv);
                    }
            }
    } else {
#pragma unroll
        for (int i = 0; i < 2; ++i) {
            int s = m0 + wm + i * 32 + l31;
            int b = s >> 11;
            int sl = s & 2047;
            int sp = (sl & ~12) | ((sl & 4) << 1) | ((sl & 8) >> 1);
#pragma unroll
            for (int j = 0; j < 2; ++j)
#pragma unroll
                for (int g = 0; g < 4; ++g) {
                    float4 bv4 = *(const float4*)&bias[n0 + wn + j * 32 + g * 8 + 4 * h];
#pragma unroll
                    for (int rr = 0; rr < 4; ++rr) {
                        int n = n0 + wn + j * 32 + g * 8 + 4 * h + rr;
                        C[(size_t)(b * 1024 + n) * 2048 + sp] =
                            (OUT_T)(acc[i][j][g * 4 + rr] + (&bv4.x)[rr]);
                    }
                }
        }
    }
}

// Flat grid 768, XCD-swizzled: id = 24*mblk + (z*8 + nblk), so
// id mod 8 = nblk -> all blocks sharing a W tile-row land on one XCD.
__global__ __launch_bounds__(256) void gemm_qkv(
    const bf16* __restrict__ qb, const bf16* __restrict__ kb, const bf16* __restrict__ vb,
    const bf16* __restrict__ Wq, const bf16* __restrict__ Wk, const bf16* __restrict__ Wv,
    const float* __restrict__ bq, const float* __restrict__ bk, const float* __restrict__ bv,
    bf16* __restrict__ Qp, bf16* __restrict__ Kp, bf16* __restrict__ VpT) {
    __shared__ bf16 Asm[128 * 64];
    __shared__ bf16 Bsm[128 * 64];
    const int id = blockIdx.x;
    const int g = id % 24;
    const int m0 = (id / 24) * 128;
    const int z = g >> 3;
    const int n0 = (g & 7) * 128;
    if (z == 2) {
        gemm32_core<bf16, true>(Asm, Bsm, vb, Wv, bv, VpT, m0, n0, 1024, 1024);
    } else {
        const bf16* A = (z == 0) ? qb : kb;
        const bf16* W = (z == 0) ? Wq : Wk;
        const float* bi = (z == 0) ? bq : bk;
        bf16* C = (z == 0) ? Qp : Kp;
        gemm32_core<bf16, false>(Asm, Bsm, A, W, bi, C, m0, n0, 1024, 1024);
    }
}

// ---- output GEMM with fused split-K combine in the A-staging ----
// 64x128 tile. A[row=token][col=dmodel] = (Op[sp0]+Op[sp1]) / (L0+L1),
// built on the fly and ds_written into the swizzled LDS layout.
// Grid 512 flat, swizzled: xt = id & 63 (same-A blocks share an XCD).
__global__ __launch_bounds__(256) void gemm_out_fused(
    const bf16* __restrict__ Op, const float* __restrict__ Lp,
    const bf16* __restrict__ W, const float* __restrict__ bias,
    float* __restrict__ C) {
    __shared__ bf16 Asm[64 * 64];
    __shared__ bf16 Bsm[128 * 64];
    const int id = blockIdx.x;
    const int m0 = (id & 63) * 64;
    const int n0 = (id >> 6) * 128;
    const int lane = threadIdx.x & 63;
    const int w = threadIdx.x >> 6;
    const int l31 = lane & 31;
    const int h = lane >> 5;
    const int x7 = l31 & 7;
    const int srow = lane >> 3;
    const int l7 = lane & 7;
    const int scol = (l7 ^ srow) * 8;
    const int wm = (w & 1) * 32;
    const int wn = (w >> 1) * 64;

    f32x16 acc[2] = {};

    for (int k0 = 0; k0 < 1024; k0 += 64) {
        // A staging: combine 2 split-K partials, normalize, swizzled ds_write
#pragma unroll
        for (int c = 0; c < 2; ++c) {
            int r = w * 16 + c * 8;
            int row = m0 + r + srow;             // token
            int colb = k0 + scol;                // dmodel col base (8-aligned)
            int b = row >> 11, q = row & 2047;
            int hh = colb >> 6, d = colb & 63;
            size_t l0i = (size_t)(b * 16 + hh) * 2048 + q;
            bf16x8 v0 = *(const bf16x8*)&Op[l0i * 64 + d];
            bf16x8 v1 = *(const bf16x8*)&Op[(l0i + 32 * 2048) * 64 + d];
            float inv = 1.0f / (Lp[l0i] + Lp[l0i + 32 * 2048]);
            bf16x8 o;
#pragma unroll
            for (int i = 0; i < 8; ++i)
                o[i] = (bf16)(((float)v0[i] + (float)v1[i]) * inv);
            *(bf16x8*)&Asm[(r + srow) * 64 + l7 * 8] = o;
        }
#pragma unroll
        for (int c = 0; c < 4; ++c) {
            int r = w * 32 + c * 8;
            gload_lds16(W + (size_t)(n0 + r + srow) * 1024 + k0 + scol, &Bsm[r * 64]);
        }
        __syncthreads();
#pragma unroll
        for (int step = 0; step < 4; ++step) {
            bf16x8 af = *(const bf16x8*)&Asm[(wm + l31) * 64 +
                                             (((step * 2 + h) ^ x7) * 8)];
            bf16x8 bfv[2];
#pragma unroll
            for (int j = 0; j < 2; ++j)
                bfv[j] = *(const bf16x8*)&Bsm[(wn + j * 32 + l31) * 64 +
                                              (((step * 2 + h) ^ x7) * 8)];
#pragma unroll
            for (int j = 0; j < 2; ++j)
                acc[j] = __builtin_amdgcn_mfma_f32_32x32x16_bf16(af, bfv[j],
                                                                 acc[j], 0, 0, 0);
        }
        __syncthreads();
    }
#pragma unroll
    for (int j = 0; j < 2; ++j) {
        int col = n0 + wn + j * 32 + l31;
        float bv = bias[col];
#pragma unroll
        for (int g = 0; g < 4; ++g)
#pragma unroll
            for (int rr = 0; rr < 4; ++rr) {
                int row = m0 + wm + rr + g * 8 + 4 * h;
                C[(size_t)row * 1024 + col] = acc[j][g * 4 + rr] + bv;
            }
    }
}

// ---------------- flash attention v4 ----------------
// Block: 256 q (4 waves x 64q), one (b,h), 1/2 of keys (split-K=2).
// Grid 512 flat, XCD-swizzled: qb = id>>6, so the 8 q-blocks of one
// (bh,sp) share id mod 8 -> same XCD -> K/V L2 reuse.
// Double-buffered K/V LDS, single barrier/iter, prefetch after barrier.
__global__ __launch_bounds__(256, 2) void attn_k(
    const bf16* __restrict__ Qp, const bf16* __restrict__ Kp,
    const bf16* __restrict__ VpT, const float* __restrict__ mb,
    bf16* __restrict__ Opart, float* __restrict__ Lpart) {
    __shared__ bf16 KV[2][2][64 * 64];  // [buf][K|V][.]
    const int g = blockIdx.x;
    const int qb = g >> 6;          // 0..7
    const int bh = (g & 63) >> 1;   // 0..31
    const int sp = g & 1;           // 0..1
    const int b = bh >> 4, hh = bh & 15;
    const int lane = threadIdx.x & 63, w = threadIdx.x >> 6;
    const int l31 = lane & 31, h = lane >> 5;
    const int x7 = l31 & 7;
    const int srow = lane >> 3, scol = ((lane & 7) ^ srow) * 8;
    const float SC = 0.125f * 1.44269504f;
    const int q0 = qb * 256;
    const int k0 = sp * 1024;

    const bf16* Kg = Kp + (size_t)(b * 2048) * 1024 + hh * 64;
    const bf16* Vg = VpT + (size_t)bh * 64 * 2048;
    const float* mbb = mb + b * 2048;

    auto stage = [&](int buf, int kt) {
#pragma unroll
        for (int c = 0; c < 2; ++c) {
            int r = w * 16 + c * 8;
            gload_lds16(Kg + (size_t)(kt + r + srow) * 1024 + scol,
                        &KV[buf][0][r * 64]);
            gload_lds16(Vg + (size_t)(r + srow) * 2048 + kt + scol,
                        &KV[buf][1][r * 64]);
        }
    };
    stage(0, k0);

    // Q B-frags for both 32-q groups: B[n=q][k=d]
    bf16x8 qf[2][4];
#pragma unroll
    for (int qg = 0; qg < 2; ++qg) {
        const bf16* Qbase =
            Qp + (size_t)(b * 2048 + q0 + w * 64 + qg * 32 + l31) * 1024 + hh * 64;
#pragma unroll
        for (int step = 0; step < 4; ++step)
            qf[qg][step] = *(const bf16x8*)(Qbase + step * 16 + h * 8);
    }

    f32x16 o[2][2] = {};  // [qg][d-group]
    float lsum[2] = {0.0f, 0.0f};

    for (int it = 0; it < 16; ++it) {
        __syncthreads();  // drains stage(it); prefetch below overlaps compute
        if (it < 15) stage((it + 1) & 1, k0 + (it + 1) * 64);
        const bf16* Ks = KV[it & 1][0];
        const bf16* Vs = KV[it & 1][1];
        const int kt = k0 + it * 64;

        bf16x8 pa[2][4];
#pragma unroll
        for (int kg = 0; kg < 2; ++kg) {
            f32x16 z0 = {}, z1 = {};
#pragma unroll
            for (int step = 0; step < 4; ++step) {
                bf16x8 kf = *(const bf16x8*)&Ks[(kg * 32 + l31) * 64 +
                                                (((step * 2 + h) ^ x7) * 8)];
                z0 = __builtin_amdgcn_mfma_f32_32x32x16_bf16(kf, qf[0][step], z0, 0, 0, 0);
                z1 = __builtin_amdgcn_mfma_f32_32x32x16_bf16(kf, qf[1][step], z1, 0, 0, 0);
            }
#pragma unroll
            for (int g = 0; g < 4; ++g) {
                float4 bia = *(const float4*)&mbb[kt + kg * 32 + g * 8 + 4 * h];
#pragma unroll
                for (int qg = 0; qg < 2; ++qg) {
                    const f32x16& z = qg ? z1 : z0;
                    float p0 = __builtin_amdgcn_exp2f(fmaf(z[g * 4 + 0], SC, bia.x));
                    float p1 = __builtin_amdgcn_exp2f(fmaf(z[g * 4 + 1], SC, bia.y));
                    float p2 = __builtin_amdgcn_exp2f(fmaf(z[g * 4 + 2], SC, bia.z));
                    float p3 = __builtin_amdgcn_exp2f(fmaf(z[g * 4 + 3], SC, bia.w));
                    lsum[qg] += (p0 + p1) + (p2 + p3);
                    bf16x8& pf = pa[qg][kg * 2 + (g >> 1)];
                    int jb = (g & 1) * 4;
                    pf[jb + 0] = (bf16)p0;
                    pf[jb + 1] = (bf16)p1;
                    pf[jb + 2] = (bf16)p2;
                    pf[jb + 3] = (bf16)p3;
                }
            }
        }
        // O[q][d] += P V : A = P C-regs (key-permuted), B = permuted VpT frags
#pragma unroll
        for (int t = 0; t < 2; ++t)
#pragma unroll
            for (int kk = 0; kk < 4; ++kk) {
                bf16x8 vf = *(const bf16x8*)&Vs[(t * 32 + l31) * 64 +
                                                (((kk * 2 + h) ^ x7) * 8)];
                o[0][t] = __builtin_amdgcn_mfma_f32_32x32x16_bf16(pa[0][kk], vf, o[0][t], 0, 0, 0);
                o[1][t] = __builtin_amdgcn_mfma_f32_32x32x16_bf16(pa[1][kk], vf, o[1][t], 0, 0, 0);
            }
    }

    // store partials (unnormalized O bf16 + lsum fp32)
    const size_t pbase = (size_t)(sp * 32 + bh) * 2048;
#pragma unroll
    for (int qg = 0; qg < 2; ++qg) {
        float ls = lsum[qg] + __shfl_xor(lsum[qg], 32, 64);
        if (h == 0)
            Lpart[pbase + q0 + w * 64 + qg * 32 + l31] = ls;
#pragma unroll
        for (int t = 0; t < 2; ++t)
#pragma unroll
            for (int g = 0; g < 4; ++g)
#pragma unroll
                for (int rr = 0; rr < 4; ++rr) {
                    int q = q0 + w * 64 + qg * 32 + rr + g * 8 + 4 * h;
                    Opart[(pbase + q) * 64 + t * 32 + l31] =
                        (bf16)o[qg][t][g * 4 + rr];
                }
    }
}

extern "C" void kernel_launch(void* const* d_in, const int* in_sizes, int n_in,
                              void* d_out, int out_size, void* d_ws, size_t ws_size,
                              hipStream_t stream) {
    const float* q   = (const float*)d_in[0];
    const float* kt  = (const float*)d_in[1];
    const float* v   = (const float*)d_in[2];
    const int* mask  = (const int*)d_in[3];
    const float* Wq  = (const float*)d_in[4];
    const float* bq  = (const float*)d_in[5];
    const float* Wk  = (const float*)d_in[6];
    const float* bk  = (const float*)d_in[7];
    const float* Wv  = (const float*)d_in[8];
    const float* bv  = (const float*)d_in[9];
    const float* Wo  = (const float*)d_in[10];
    const float* bo  = (const float*)d_in[11];
    float* out = (float*)d_out;

    char* ws = (char*)d_ws;
    const size_t SZ_IN = 4096ull * 1024 * 2;  // 8 MB bf16 activation
    const size_t SZ_W  = 1024ull * 1024 * 2;  // 2 MB bf16 weight
    bf16* qb  = (bf16*)(ws + 0 * SZ_IN);
    bf16* kb  = (bf16*)(ws + 1 * SZ_IN);
    bf16* vb  = (bf16*)(ws + 2 * SZ_IN);
    bf16* Wqb = (bf16*)(ws + 3 * SZ_IN);
    bf16* Wkb = (bf16*)(ws + 3 * SZ_IN + 1 * SZ_W);
    bf16* Wvb = (bf16*)(ws + 3 * SZ_IN + 2 * SZ_W);
    bf16* Wob = (bf16*)(ws + 3 * SZ_IN + 3 * SZ_W);
    bf16* Qp  = (bf16*)(ws + 3 * SZ_IN + 4 * SZ_W);
    bf16* Kp  = (bf16*)(ws + 4 * SZ_IN + 4 * SZ_W);
    bf16* VpT = (bf16*)(ws + 5 * SZ_IN + 4 * SZ_W);
    float* mb = (float*)(ws + 6 * SZ_IN + 4 * SZ_W);          // 16 KB (pad 1 MB)
    char*  p0 = ws + 6 * SZ_IN + 4 * SZ_W + (1 << 20);
    bf16* Opart = (bf16*)p0;                                   // 2*32*2048*64*2 = 16.8 MB
    float* Lpart = (float*)(p0 + 2ull * 32 * 2048 * 64 * 2);   // 0.5 MB

    const int NIN = 4096 * 1024, NW = 1024 * 1024;
    cast8_k<<<dim3(NIN / 2048, 1, 8), 256, 0, stream>>>(
        q, kt, v, Wq, Wk, Wv, Wo, qb, kb, vb, Wqb, Wkb, Wvb, Wob,
        mask, mb, NIN, NW);

    gemm_qkv<<<dim3(768), 256, 0, stream>>>(qb, kb, vb, Wqb, Wkb, Wvb,
                                            bq, bk, bv, Qp, Kp, VpT);
    attn_k<<<dim3(512), 256, 0, stream>>>(Qp, Kp, VpT, mb, Opart, Lpart);
    gemm_out_fused<<<dim3(512), 256, 0, stream>>>(Opart, Lpart, Wob, bo, out);
}